// Round 4
// baseline (498.852 us; speedup 1.0000x reference)
//
#include <hip/hip_runtime.h>

#define SEQ    256
#define BATCHN 2048
#define NIN    64
#define H      128
#define NOUT   64
#define TOUT   128
#define BT     16     // batch rows per block
#define ASTR   200    // LDS row stride in halfs (192 + 8 pad)

using half8 = _Float16 __attribute__((ext_vector_type(8)));
using f32x4 = float    __attribute__((ext_vector_type(4)));

__device__ __forceinline__ float sigf(float v) {
    return __builtin_amdgcn_rcpf(1.f + __expf(-v));
}
__device__ __forceinline__ float tanhfast(float v) {
    return 1.f - 2.f * __builtin_amdgcn_rcpf(1.f + __expf(2.f * v));
}

__device__ __forceinline__ half8 ldfrag8(const float* __restrict__ p) {
    half8 r;
#pragma unroll
    for (int e = 0; e < 8; ++e) r[e] = (_Float16)p[e];
    return r;
}

// Fused seq2seq: encoder (256 steps) + decoder (128 steps), one persistent kernel.
// Wave w owns hidden slice [16w,16w+16); MFMA 16x16x32 f16 maps (verified on-HW by
// the round-2 probe battery + round-3 self-calibration): A row = lane&15,
// B col = lane&15, D row = 4*(lane>>4)+r, D col = lane&15.
__global__ __launch_bounds__(512, 2) void seq2seq_fused(
    const float* __restrict__ x,
    const float* __restrict__ eWih, const float* __restrict__ eWhh, const float* __restrict__ eb,
    const float* __restrict__ dWih, const float* __restrict__ dWhh, const float* __restrict__ db,
    const float* __restrict__ oW,   const float* __restrict__ obv,
    float* __restrict__ out)
{
    __shared__ __align__(16) _Float16 als[2][BT][ASTR]; // [b][k], k: 0..63 = x/y, 64..191 = h

    const int tid  = threadIdx.x;
    const int lane = tid & 63;
    const int w    = tid >> 6;
    const int jl   = lane & 15;
    const int lg   = lane >> 4;
    const int b0   = blockIdx.x * BT;

    // ---------------- encoder weights -> resident VGPR fragments ----------------
    half8 wf[4][6];   // [gate][k-chunk]
    float bq[4];
#pragma unroll
    for (int q = 0; q < 4; ++q) {
        const int j = q * H + w * 16 + jl;
#pragma unroll
        for (int kc = 0; kc < 2; ++kc)
            wf[q][kc] = ldfrag8(eWih + j * NIN + kc * 32 + lg * 8);
#pragma unroll
        for (int kc = 2; kc < 6; ++kc)
            wf[q][kc] = ldfrag8(eWhh + j * H + (kc - 2) * 32 + lg * 8);
        bq[q] = eb[j];
    }

    float c[4] = {0.f, 0.f, 0.f, 0.f};  // cell state, rows 4*lg+r, col jl (wave slice w)

    for (int i = tid; i < 2 * BT * ASTR; i += 512) ((_Float16*)als)[i] = (_Float16)0.f;
    __syncthreads();
    {
        const int xi = tid >> 5, xn = (tid & 31) * 2;
        const float2 xv = *(const float2*)(x + (b0 + xi) * NIN + xn);
        als[0][xi][xn]     = (_Float16)xv.x;
        als[0][xi][xn + 1] = (_Float16)xv.y;
    }
    __syncthreads();

    // ---------------- encoder: 256 steps, 1 barrier/step ----------------
    for (int t = 0; t < SEQ; ++t) {
        const int cur = t & 1, nxt = cur ^ 1;

        const int xi = tid >> 5, xn = (tid & 31) * 2;
        float2 xv = make_float2(0.f, 0.f);
        if (t + 1 < SEQ)
            xv = *(const float2*)(x + ((t + 1) * BATCHN + b0 + xi) * NIN + xn);

        half8 af[6];
#pragma unroll
        for (int kc = 0; kc < 6; ++kc)
            af[kc] = *(const half8*)&als[cur][jl][kc * 32 + lg * 8];

        f32x4 ac[4];
#pragma unroll
        for (int q = 0; q < 4; ++q) {
            f32x4 a = {bq[q], bq[q], bq[q], bq[q]};
#pragma unroll
            for (int kc = 0; kc < 6; ++kc)
                a = __builtin_amdgcn_mfma_f32_16x16x32_f16(af[kc], wf[q][kc], a, 0, 0, 0);
            ac[q] = a;
        }

#pragma unroll
        for (int r = 0; r < 4; ++r) {
            const float ig = sigf(ac[0][r]);
            const float fg = sigf(ac[1][r]);
            const float gg = tanhfast(ac[2][r]);
            const float og = sigf(ac[3][r]);
            c[r] = fg * c[r] + ig * gg;
            const float hv = og * tanhfast(c[r]);
            als[nxt][lg * 4 + r][NIN + w * 16 + jl] = (_Float16)hv;
        }
        als[nxt][xi][xn]     = (_Float16)xv.x;
        als[nxt][xi][xn + 1] = (_Float16)xv.y;
        __syncthreads();
    }

    // ---------------- decoder weights (reuse registers) ----------------
#pragma unroll
    for (int q = 0; q < 4; ++q) {
        const int j = q * H + w * 16 + jl;
#pragma unroll
        for (int kc = 0; kc < 2; ++kc)
            wf[q][kc] = ldfrag8(dWih + j * NIN + kc * 32 + lg * 8);
#pragma unroll
        for (int kc = 2; kc < 6; ++kc)
            wf[q][kc] = ldfrag8(dWhh + j * H + (kc - 2) * 32 + lg * 8);
        bq[q] = db[j];
    }
    half8 of[4];
    float oB = 0.f;
    if (w < 4) {  // waves 0..3 own the y-GEMM
        const int j = w * 16 + jl;
#pragma unroll
        for (int kc = 0; kc < 4; ++kc)
            of[kc] = ldfrag8(oW + j * H + kc * 32 + lg * 8);
        oB = obv[j];
    }

    // ---------------- decoder: 128 steps, 2 barriers/step ----------------
    for (int s = 0; s < TOUT; ++s) {
        const int cur = s & 1, nxt = cur ^ 1;

        half8 af[6];
#pragma unroll
        for (int kc = 0; kc < 6; ++kc)
            af[kc] = *(const half8*)&als[cur][jl][kc * 32 + lg * 8];

        f32x4 ac[4];
#pragma unroll
        for (int q = 0; q < 4; ++q) {
            f32x4 a = {bq[q], bq[q], bq[q], bq[q]};
#pragma unroll
            for (int kc = 0; kc < 6; ++kc)
                a = __builtin_amdgcn_mfma_f32_16x16x32_f16(af[kc], wf[q][kc], a, 0, 0, 0);
            ac[q] = a;
        }

#pragma unroll
        for (int r = 0; r < 4; ++r) {
            const float ig = sigf(ac[0][r]);
            const float fg = sigf(ac[1][r]);
            const float gg = tanhfast(ac[2][r]);
            const float og = sigf(ac[3][r]);
            c[r] = fg * c[r] + ig * gg;
            const float hv = og * tanhfast(c[r]);
            als[nxt][lg * 4 + r][NIN + w * 16 + jl] = (_Float16)hv;
        }
        __syncthreads();  // h_new visible to y-GEMM waves

        if (w < 4) {
            half8 hf[4];
#pragma unroll
            for (int kc = 0; kc < 4; ++kc)
                hf[kc] = *(const half8*)&als[nxt][jl][NIN + kc * 32 + lg * 8];
            f32x4 ya = {oB, oB, oB, oB};
#pragma unroll
            for (int kc = 0; kc < 4; ++kc)
                ya = __builtin_amdgcn_mfma_f32_16x16x32_f16(hf[kc], of[kc], ya, 0, 0, 0);
            const int j = w * 16 + jl;
#pragma unroll
            for (int r = 0; r < 4; ++r) {
                const int row = lg * 4 + r;
                const float yv = ya[r];
                als[nxt][row][j] = (_Float16)yv;              // feedback -> next x_t
                out[((b0 + row) * NOUT + j) * TOUT + s] = yv; // f32 output [B][N_OUT][T]
            }
        }
        __syncthreads();  // y visible before next step's gate GEMM
    }
}

extern "C" void kernel_launch(void* const* d_in, const int* in_sizes, int n_in,
                              void* d_out, int out_size, void* d_ws, size_t ws_size,
                              hipStream_t stream) {
    (void)in_sizes; (void)n_in; (void)out_size; (void)d_ws; (void)ws_size;
    const float* x    = (const float*)d_in[0];
    const float* eWih = (const float*)d_in[1];
    const float* eWhh = (const float*)d_in[2];
    const float* eb   = (const float*)d_in[3];
    const float* dWih = (const float*)d_in[4];
    const float* dWhh = (const float*)d_in[5];
    const float* db   = (const float*)d_in[6];
    const float* oW   = (const float*)d_in[7];
    const float* ob   = (const float*)d_in[8];

    seq2seq_fused<<<BATCHN / BT, 512, 0, stream>>>(
        x, eWih, eWhh, eb, dWih, dWhh, db, oW, ob, (float*)d_out);
}

// Round 5
// 397.618 us; speedup vs baseline: 1.2546x; 1.2546x over previous
//
#include <hip/hip_runtime.h>

#define SEQ    256
#define BATCHN 2048
#define NIN    64
#define H      128
#define NOUT   64
#define TOUT   128
#define BT     16     // batch rows per block
#define ASTR   200    // LDS row stride in halfs (192 + 8 pad)
#define TCH    16     // decoder steps buffered before a coalesced flush

using half8 = _Float16 __attribute__((ext_vector_type(8)));
using f32x4 = float    __attribute__((ext_vector_type(4)));

__device__ __forceinline__ float sigf(float v) {
    return __builtin_amdgcn_rcpf(1.f + __expf(-v));
}
__device__ __forceinline__ float tanhfast(float v) {
    return 1.f - 2.f * __builtin_amdgcn_rcpf(1.f + __expf(2.f * v));
}

__device__ __forceinline__ half8 ldfrag8(const float* __restrict__ p) {
    half8 r;
#pragma unroll
    for (int e = 0; e < 8; ++e) r[e] = (_Float16)p[e];
    return r;
}

// Fused seq2seq: encoder (256 steps) + decoder (128 steps), one persistent kernel.
// MFMA 16x16x32 f16 maps (HW-verified rounds 2-3): A row = lane&15, B col = lane&15,
// D row = 4*(lane>>4)+r, D col = lane&15.
// Round-5 change: decoder output staged in LDS (f16) and flushed every TCH steps as
// fully-covered 64B lines -> kills the 20x write amplification seen in round 4.
__global__ __launch_bounds__(512, 2) void seq2seq_fused(
    const float* __restrict__ x,
    const float* __restrict__ eWih, const float* __restrict__ eWhh, const float* __restrict__ eb,
    const float* __restrict__ dWih, const float* __restrict__ dWhh, const float* __restrict__ db,
    const float* __restrict__ oW,   const float* __restrict__ obv,
    float* __restrict__ out)
{
    __shared__ __align__(16) _Float16 als[2][BT][ASTR];  // [b][k], k: 0..63 = x/y, 64..191 = h
    __shared__ __align__(16) _Float16 ybuf[TCH][BT][68]; // staged decoder outputs [tt][row][j]

    const int tid  = threadIdx.x;
    const int lane = tid & 63;
    const int w    = tid >> 6;
    const int jl   = lane & 15;
    const int lg   = lane >> 4;
    const int b0   = blockIdx.x * BT;

    // ---------------- encoder weights -> resident VGPR fragments ----------------
    half8 wf[4][6];   // [gate][k-chunk]
    float bq[4];
#pragma unroll
    for (int q = 0; q < 4; ++q) {
        const int j = q * H + w * 16 + jl;
#pragma unroll
        for (int kc = 0; kc < 2; ++kc)
            wf[q][kc] = ldfrag8(eWih + j * NIN + kc * 32 + lg * 8);
#pragma unroll
        for (int kc = 2; kc < 6; ++kc)
            wf[q][kc] = ldfrag8(eWhh + j * H + (kc - 2) * 32 + lg * 8);
        bq[q] = eb[j];
    }

    float c[4] = {0.f, 0.f, 0.f, 0.f};  // cell state, rows 4*lg+r, col jl (wave slice w)

    for (int i = tid; i < 2 * BT * ASTR; i += 512) ((_Float16*)als)[i] = (_Float16)0.f;
    __syncthreads();
    {
        const int xi = tid >> 5, xn = (tid & 31) * 2;
        const float2 xv = *(const float2*)(x + (b0 + xi) * NIN + xn);
        als[0][xi][xn]     = (_Float16)xv.x;
        als[0][xi][xn + 1] = (_Float16)xv.y;
    }
    __syncthreads();

    // ---------------- encoder: 256 steps, 1 barrier/step ----------------
    for (int t = 0; t < SEQ; ++t) {
        const int cur = t & 1, nxt = cur ^ 1;

        const int xi = tid >> 5, xn = (tid & 31) * 2;
        float2 xv = make_float2(0.f, 0.f);
        if (t + 1 < SEQ)
            xv = *(const float2*)(x + ((t + 1) * BATCHN + b0 + xi) * NIN + xn);

        half8 af[6];
#pragma unroll
        for (int kc = 0; kc < 6; ++kc)
            af[kc] = *(const half8*)&als[cur][jl][kc * 32 + lg * 8];

        f32x4 ac[4];
#pragma unroll
        for (int q = 0; q < 4; ++q) {
            f32x4 a = {bq[q], bq[q], bq[q], bq[q]};
#pragma unroll
            for (int kc = 0; kc < 6; ++kc)
                a = __builtin_amdgcn_mfma_f32_16x16x32_f16(af[kc], wf[q][kc], a, 0, 0, 0);
            ac[q] = a;
        }

#pragma unroll
        for (int r = 0; r < 4; ++r) {
            const float ig = sigf(ac[0][r]);
            const float fg = sigf(ac[1][r]);
            const float gg = tanhfast(ac[2][r]);
            const float og = sigf(ac[3][r]);
            c[r] = fg * c[r] + ig * gg;
            const float hv = og * tanhfast(c[r]);
            als[nxt][lg * 4 + r][NIN + w * 16 + jl] = (_Float16)hv;
        }
        als[nxt][xi][xn]     = (_Float16)xv.x;
        als[nxt][xi][xn + 1] = (_Float16)xv.y;
        __syncthreads();
    }

    // ---------------- decoder weights (reuse registers) ----------------
#pragma unroll
    for (int q = 0; q < 4; ++q) {
        const int j = q * H + w * 16 + jl;
#pragma unroll
        for (int kc = 0; kc < 2; ++kc)
            wf[q][kc] = ldfrag8(dWih + j * NIN + kc * 32 + lg * 8);
#pragma unroll
        for (int kc = 2; kc < 6; ++kc)
            wf[q][kc] = ldfrag8(dWhh + j * H + (kc - 2) * 32 + lg * 8);
        bq[q] = db[j];
    }
    half8 of[4];
    float oB = 0.f;
    if (w < 4) {  // waves 0..3 own the y-GEMM
        const int j = w * 16 + jl;
#pragma unroll
        for (int kc = 0; kc < 4; ++kc)
            of[kc] = ldfrag8(oW + j * H + kc * 32 + lg * 8);
        oB = obv[j];
    }

    // ---------------- decoder: 128 steps, 2 barriers/step ----------------
    for (int s = 0; s < TOUT; ++s) {
        const int cur = s & 1, nxt = cur ^ 1;

        half8 af[6];
#pragma unroll
        for (int kc = 0; kc < 6; ++kc)
            af[kc] = *(const half8*)&als[cur][jl][kc * 32 + lg * 8];

        f32x4 ac[4];
#pragma unroll
        for (int q = 0; q < 4; ++q) {
            f32x4 a = {bq[q], bq[q], bq[q], bq[q]};
#pragma unroll
            for (int kc = 0; kc < 6; ++kc)
                a = __builtin_amdgcn_mfma_f32_16x16x32_f16(af[kc], wf[q][kc], a, 0, 0, 0);
            ac[q] = a;
        }

#pragma unroll
        for (int r = 0; r < 4; ++r) {
            const float ig = sigf(ac[0][r]);
            const float fg = sigf(ac[1][r]);
            const float gg = tanhfast(ac[2][r]);
            const float og = sigf(ac[3][r]);
            c[r] = fg * c[r] + ig * gg;
            const float hv = og * tanhfast(c[r]);
            als[nxt][lg * 4 + r][NIN + w * 16 + jl] = (_Float16)hv;
        }
        __syncthreads();  // h_new visible to y-GEMM waves

        if (w < 4) {
            half8 hf[4];
#pragma unroll
            for (int kc = 0; kc < 4; ++kc)
                hf[kc] = *(const half8*)&als[nxt][jl][NIN + kc * 32 + lg * 8];
            f32x4 ya = {oB, oB, oB, oB};
#pragma unroll
            for (int kc = 0; kc < 4; ++kc)
                ya = __builtin_amdgcn_mfma_f32_16x16x32_f16(hf[kc], of[kc], ya, 0, 0, 0);
            const int j = w * 16 + jl;
            const int tt = s & (TCH - 1);
#pragma unroll
            for (int r = 0; r < 4; ++r) {
                const int row = lg * 4 + r;
                const float yv = ya[r];
                als[nxt][row][j] = (_Float16)yv;     // feedback -> next x_t
                ybuf[tt][row][j] = (_Float16)yv;     // staged output (flushed coalesced)
            }
        }
        __syncthreads();  // y visible before next step's gate GEMM; orders ybuf vs flush

        // coalesced flush: every TCH steps, write [row][j][t0..t0+15] as full 64B lines
        if ((s & (TCH - 1)) == (TCH - 1)) {
            const int t0 = s & ~(TCH - 1);
#pragma unroll
            for (int it = 0; it < 8; ++it) {
                const int slot = it * 512 + tid;   // 0..4095
                const int pair = slot >> 2;        // (row,j): 0..1023
                const int tq   = slot & 3;
                const int row  = pair >> 6;
                const int j    = pair & 63;
                float4 v;
                v.x = (float)ybuf[tq * 4 + 0][row][j];
                v.y = (float)ybuf[tq * 4 + 1][row][j];
                v.z = (float)ybuf[tq * 4 + 2][row][j];
                v.w = (float)ybuf[tq * 4 + 3][row][j];
                *(float4*)(out + ((size_t)(b0 + row) * NOUT + j) * TOUT + t0 + tq * 4) = v;
            }
            // next ybuf writes happen after the next step's first barrier -> no WAR hazard
        }
    }
}

extern "C" void kernel_launch(void* const* d_in, const int* in_sizes, int n_in,
                              void* d_out, int out_size, void* d_ws, size_t ws_size,
                              hipStream_t stream) {
    (void)in_sizes; (void)n_in; (void)out_size; (void)d_ws; (void)ws_size;
    const float* x    = (const float*)d_in[0];
    const float* eWih = (const float*)d_in[1];
    const float* eWhh = (const float*)d_in[2];
    const float* eb   = (const float*)d_in[3];
    const float* dWih = (const float*)d_in[4];
    const float* dWhh = (const float*)d_in[5];
    const float* db   = (const float*)d_in[6];
    const float* oW   = (const float*)d_in[7];
    const float* ob   = (const float*)d_in[8];

    seq2seq_fused<<<BATCHN / BT, 512, 0, stream>>>(
        x, eWih, eWhh, eb, dWih, dWhh, db, oW, ob, (float*)d_out);
}